// Round 7
// baseline (748.927 us; speedup 1.0000x reference)
//
#include <hip/hip_runtime.h>
#include <hip/hip_bf16.h>

typedef unsigned long long ull;

// Problem constants (from reference)
#define N_TRIALS   8
#define T_TOTAL    600
#define N_NEURONS  30000
#define NEED_N     25000        // sample_ids ∈ [0, 25000); rest of row never probed
#define T_USE      500
#define N_SAMPLES  50
#define MAX_COUNT  200
#define N_BINS     16
#define GROUPS     98           // 1KB segments per row (98*256 = 25088 floats >= 25000)
#define HALF_SEGS  49           // segments per wave (2 waves per row)
#define WPR        (GROUPS * 4) // u64 words per row bitmap (392)
#define N_ROWS     (N_TRIALS * T_USE)              // 4000
#define EPS_D      1e-7

__device__ __constant__ int BIN_SIZES[N_BINS] = {1,1,2,3,4,6,9,13,18,26,38,55,78,113,162,234};

// K0: cnts[s] = sum(mask[s][:]) (prefix mask -> count fully describes it).
__global__ __launch_bounds__(256) void cnt_kernel(
    const float* __restrict__ mask, int* __restrict__ cnts)
{
    int w    = (blockIdx.x * 256 + threadIdx.x) >> 6;
    int lane = threadIdx.x & 63;
    if (w >= N_SAMPLES) return;
    const float* m = mask + w * MAX_COUNT;
    float sum = 0.f;
    for (int j = lane; j < MAX_COUNT; j += 64) sum += m[j];
    for (int k = 32; k; k >>= 1) sum += __shfl_xor(sum, k);
    if (lane == 0) cnts[w] = (int)(sum + 0.5f);
}

// K1: resident streaming compress. 2000 blocks x 256 = 8000 waves (31.25/CU,
// fully resident). Each wave owns half a row: 49 contiguous 1KB segments.
// Row math hoisted out of the loop; inner loop = independent float4 loads
// (7 in flight) + 4 ballots + lane-0 32B store. All padded quads stay inside
// the row's 30000 floats; bits for neurons >= 25000 are never probed.
// Bit mapping for neuron n: word = row*WPR + ((n>>8)<<2 | (n&3)), bit (n>>2)&63.
__global__ __launch_bounds__(256) void compress_kernel(
    const float* __restrict__ spikes, ull* __restrict__ bm)
{
    int wid  = (blockIdx.x * 256 + threadIdx.x) >> 6;   // 0..7999
    int lane = threadIdx.x & 63;
    int r    = wid >> 1;                  // row 0..3999  (r = tr*T_USE + t)
    int h    = wid & 1;                   // which half of the row
    int tr   = r / T_USE;
    int rowg = r + tr * (T_TOTAL - T_USE);                // tr*600 + t
    const float* rowp = spikes + (size_t)rowg * N_NEURONS;
    ull* dstrow = bm + (size_t)r * WPR;

    int g0 = h * HALF_SEGS;
    for (int kk = 0; kk < 7; ++kk) {
#pragma unroll
        for (int j = 0; j < 7; ++j) {
            int g = g0 + kk * 7 + j;
            float4 v = *reinterpret_cast<const float4*>(rowp + ((g << 6) + lane) * 4);
            ull b0 = __ballot(v.x != 0.f);
            ull b1 = __ballot(v.y != 0.f);
            ull b2 = __ballot(v.z != 0.f);
            ull b3 = __ballot(v.w != 0.f);
            if (lane == 0) {
                ulonglong2 p0; p0.x = b0; p0.y = b1;
                ulonglong2 p1; p1.x = b2; p1.y = b3;
                *reinterpret_cast<ulonglong2*>(dstrow + g * 4)     = p0;
                *reinterpret_cast<ulonglong2*>(dstrow + g * 4 + 2) = p1;
            }
        }
    }
}

// K2: one block per t. Stage all 8 trial-row bitmaps (25 KB) into LDS
// (coalesced), then each wave computes counts for samples s = wv, wv+4, ...
// via LDS bit probes + popc(ballot). No scattered HBM traffic at all.
__global__ __launch_bounds__(256) void probe_kernel(
    const ull* __restrict__ bm,
    const int* __restrict__ trials,
    const int* __restrict__ ids,
    const int* __restrict__ cnts,
    float*     __restrict__ sel)
{
    __shared__ ull lbm[N_TRIALS][WPR];
    int t    = blockIdx.x;
    int tid  = threadIdx.x;
    int wv   = tid >> 6;
    int lane = tid & 63;

    for (int tr = 0; tr < N_TRIALS; ++tr)
        for (int j = tid; j < WPR; j += 256)
            lbm[tr][j] = bm[(size_t)(tr * T_USE + t) * WPR + j];
    __syncthreads();

    for (int s = wv; s < N_SAMPLES; s += 4) {
        int tr  = trials[s];
        int cnt = cnts[s];
        const int* sid = ids + s * MAX_COUNT;
        int c = 0;
        for (int base = 0; base < MAX_COUNT; base += 64) {
            int j = base + lane;
            bool pred = false;
            if (j < cnt) {
                int n = sid[j];
                ull w = lbm[tr][((n >> 8) << 2) | (n & 3)];
                pred = (w >> ((n >> 2) & 63)) & 1ull;
            }
            c += __popcll(__ballot(pred));
        }
        if (lane == 0) sel[s * T_USE + t] = (float)c;
    }
}

// K3: one wave per (bin, sample): population var/mean -> fano[bin*50+s].
__global__ __launch_bounds__(256) void fano_stage(
    const float* __restrict__ sel,
    float*       __restrict__ fano)
{
    int w    = (blockIdx.x * 256 + threadIdx.x) >> 6;
    int lane = threadIdx.x & 63;
    if (w >= N_BINS * N_SAMPLES) return;
    int bin = w / N_SAMPLES;
    int s   = w % N_SAMPLES;
    int bs  = BIN_SIZES[bin];
    int nb  = T_USE / bs;
    const float* rowp = sel + s * T_USE;

    double sum = 0.0, sumsq = 0.0;
    for (int b = lane; b < nb; b += 64) {
        double c = 0.0;
        int base = b * bs;
        for (int q = 0; q < bs; ++q) c += (double)rowp[base + q];
        sum   += c;
        sumsq += c * c;
    }
    for (int k = 32; k; k >>= 1) {
        sum   += __shfl_xor(sum,   k);
        sumsq += __shfl_xor(sumsq, k);
    }
    if (lane == 0) {
        double mean = sum / nb;
        double var  = sumsq / nb - mean * mean;
        double m2   = mean < EPS_D ? EPS_D : mean;
        fano[w] = (float)(var / m2);
    }
}

// K4: fanos_mean per bin, MSE vs experimental, out = 10*mse. One wave.
__global__ void final_kernel(
    const float* __restrict__ fano,
    const float* __restrict__ expf,
    float*       __restrict__ out)
{
    int tid = threadIdx.x;   // 64 threads
    double d2 = 0.0;
    if (tid < N_BINS) {
        double acc = 0.0;
        for (int s = 0; s < N_SAMPLES; ++s) acc += (double)fano[tid * N_SAMPLES + s];
        double fm   = acc / N_SAMPLES;
        double diff = (double)expf[tid] - fm;
        d2 = diff * diff;
    }
    for (int k = 32; k; k >>= 1) d2 += __shfl_xor(d2, k);
    if (tid == 0) out[0] = (float)(10.0 * d2 / N_BINS);
}

extern "C" void kernel_launch(void* const* d_in, const int* in_sizes, int n_in,
                              void* d_out, int out_size, void* d_ws, size_t ws_size,
                              hipStream_t stream)
{
    const float* spikes = (const float*)d_in[0];   // (8, 600, 30000) f32
    const float* expf   = (const float*)d_in[1];   // (16,) f32
    const int*   trials = (const int*)d_in[2];     // (50,) i32
    const int*   ids    = (const int*)d_in[3];     // (50, 200) i32 (harness-converted)
    const float* mask   = (const float*)d_in[4];   // (50, 200) f32
    float* out = (float*)d_out;

    ull*   bm   = (ull*)d_ws;                      // 4000*392 u64 = 12.544 MB
    float* sel  = (float*)(bm + (size_t)N_ROWS * WPR); // 25000 f32
    float* fano = sel + N_SAMPLES * T_USE;         // 800 f32
    int*   cnts = (int*)(fano + N_BINS * N_SAMPLES); // 50 i32

    cnt_kernel<<<(N_SAMPLES * 64 + 255) / 256, 256, 0, stream>>>(mask, cnts);

    compress_kernel<<<(N_ROWS * 2 * 64) / 256, 256, 0, stream>>>(spikes, bm);

    probe_kernel<<<T_USE, 256, 0, stream>>>(bm, trials, ids, cnts, sel);

    fano_stage<<<(N_BINS * N_SAMPLES * 64 + 255) / 256, 256, 0, stream>>>(sel, fano);

    final_kernel<<<1, 64, 0, stream>>>(fano, expf, out);
}

// Round 8
// 681.692 us; speedup vs baseline: 1.0986x; 1.0986x over previous
//
#include <hip/hip_runtime.h>
#include <hip/hip_bf16.h>

// Problem constants (from reference)
#define N_TRIALS   8
#define T_TOTAL    600
#define N_NEURONS  30000
#define T_USE      500          // T_END - T_START
#define N_SAMPLES  50
#define MAX_COUNT  200
#define N_BINS     16
#define GROUP      16           // lanes per (s,t) output
#define EPS_D      1e-7

__device__ __constant__ int BIN_SIZES[N_BINS] = {1,1,2,3,4,6,9,13,18,26,38,55,78,113,162,234};

// K0: cnts[s] = sum(mask[s][:]) (prefix mask -> count fully describes it).
__global__ __launch_bounds__(256) void cnt_kernel(
    const float* __restrict__ mask, int* __restrict__ cnts)
{
    int w    = (blockIdx.x * 256 + threadIdx.x) >> 6;
    int lane = threadIdx.x & 63;
    if (w >= N_SAMPLES) return;
    const float* m = mask + w * MAX_COUNT;
    float sum = 0.f;
    for (int j = lane; j < MAX_COUNT; j += 64) sum += m[j];
    for (int k = 32; k; k >>= 1) sum += __shfl_xor(sum, k);
    if (lane == 0) cnts[w] = (int)(sum + 0.5f);
}

// K1: sel[s*500+t] = sum_{j<cnt_s} spikes[trial_s][t][ids[s][j]]
// 16 lanes per (s,t); branch-free loop, all gathers independent.
// This is latency-bound at the per-CU outstanding-miss-queue limit:
// ~1.75M distinct 64B lines, each read exactly once (no reuse possible).
// GROUP=8 vs 16 measured identical -> queue-limited, not occupancy-limited.
__global__ __launch_bounds__(256) void sel_kernel(
    const float* __restrict__ spikes,
    const int*   __restrict__ trials,
    const int*   __restrict__ ids,
    const int*   __restrict__ cnts,
    float*       __restrict__ sel)
{
    int u = blockIdx.x * 256 + threadIdx.x;
    int g = u & (GROUP - 1);
    int v = u >> 4;            // (s,t) linear index, 0..24999
    if (v >= N_SAMPLES * T_USE) return;
    int t = v % T_USE;
    int s = v / T_USE;

    int trial = trials[s];
    int cnt   = cnts[s];
    const float* row = spikes + (size_t)trial * (T_TOTAL * N_NEURONS)
                              + (size_t)t * N_NEURONS;
    const int*   sid = ids + s * MAX_COUNT;

    float acc = 0.f;
    for (int j = g; j < cnt; j += GROUP)
        acc += row[sid[j]];

    acc += __shfl_xor(acc, 1);
    acc += __shfl_xor(acc, 2);
    acc += __shfl_xor(acc, 4);
    acc += __shfl_xor(acc, 8);
    if (g == 0) sel[v] = acc;
}

// K2: one wave per (bin, sample): bin the 500-long row, population var/mean ->
// fano[bin*50+s]. Lanes parallelize over the nb bins.
__global__ __launch_bounds__(256) void fano_stage(
    const float* __restrict__ sel,
    float*       __restrict__ fano)
{
    int w    = (blockIdx.x * 256 + threadIdx.x) >> 6;
    int lane = threadIdx.x & 63;
    if (w >= N_BINS * N_SAMPLES) return;
    int bin = w / N_SAMPLES;
    int s   = w % N_SAMPLES;
    int bs  = BIN_SIZES[bin];
    int nb  = T_USE / bs;
    const float* rowp = sel + s * T_USE;

    double sum = 0.0, sumsq = 0.0;
    for (int b = lane; b < nb; b += 64) {
        double c = 0.0;
        int base = b * bs;
        for (int q = 0; q < bs; ++q) c += (double)rowp[base + q];
        sum   += c;
        sumsq += c * c;
    }
    for (int k = 32; k; k >>= 1) {
        sum   += __shfl_xor(sum,   k);
        sumsq += __shfl_xor(sumsq, k);
    }
    if (lane == 0) {
        double mean = sum / nb;
        double var  = sumsq / nb - mean * mean;
        double m2   = mean < EPS_D ? EPS_D : mean;
        fano[w] = (float)(var / m2);
    }
}

// K3: fanos_mean per bin, MSE vs experimental, out = 10*mse. One wave.
__global__ void final_kernel(
    const float* __restrict__ fano,
    const float* __restrict__ expf,
    float*       __restrict__ out)
{
    int tid = threadIdx.x;   // 64 threads
    double d2 = 0.0;
    if (tid < N_BINS) {
        double acc = 0.0;
        for (int s = 0; s < N_SAMPLES; ++s) acc += (double)fano[tid * N_SAMPLES + s];
        double fm   = acc / N_SAMPLES;
        double diff = (double)expf[tid] - fm;
        d2 = diff * diff;
    }
    for (int k = 32; k; k >>= 1) d2 += __shfl_xor(d2, k);
    if (tid == 0) out[0] = (float)(10.0 * d2 / N_BINS);
}

extern "C" void kernel_launch(void* const* d_in, const int* in_sizes, int n_in,
                              void* d_out, int out_size, void* d_ws, size_t ws_size,
                              hipStream_t stream)
{
    const float* spikes = (const float*)d_in[0];   // (8, 600, 30000) f32
    const float* expf   = (const float*)d_in[1];   // (16,) f32
    const int*   trials = (const int*)d_in[2];     // (50,) i32
    const int*   ids    = (const int*)d_in[3];     // (50, 200) i32 (harness-converted)
    const float* mask   = (const float*)d_in[4];   // (50, 200) f32
    float* out = (float*)d_out;

    float* sel  = (float*)d_ws;                      // 25000 f32
    float* fano = sel + N_SAMPLES * T_USE;           // 800 f32
    int*   cnts = (int*)(fano + N_BINS * N_SAMPLES); // 50 i32

    cnt_kernel<<<(N_SAMPLES * 64 + 255) / 256, 256, 0, stream>>>(mask, cnts);

    const int total = N_SAMPLES * T_USE * GROUP;   // 400,000 threads
    sel_kernel<<<(total + 255) / 256, 256, 0, stream>>>(spikes, trials, ids, cnts, sel);

    fano_stage<<<(N_BINS * N_SAMPLES * 64 + 255) / 256, 256, 0, stream>>>(sel, fano);

    final_kernel<<<1, 64, 0, stream>>>(fano, expf, out);
}